// Round 12
// baseline (210.831 us; speedup 1.0000x reference)
//
#include <hip/hip_runtime.h>
#include <stdint.h>

#define DEVFN __device__ __forceinline__

typedef unsigned short u16;
typedef __bf16 bf16_t;
typedef bf16_t bf16x8 __attribute__((ext_vector_type(8)));
typedef float  f32x4  __attribute__((ext_vector_type(4)));

static constexpr int Bb = 8, Nn = 3072, Cc = 768;
static constexpr int Mr = Bb * Nn;      // 24576 rows
static constexpr int C3 = 3 * Cc;       // 2304
static constexpr int NB = 1024;         // dilation stride

DEVFN u16 f2bf_rne(float f) {
  uint32_t u = __builtin_bit_cast(uint32_t, f);
  u += 0x7FFFu + ((u >> 16) & 1u);
  return (u16)(u >> 16);
}
DEVFN float bf2f(u16 v) {
  uint32_t u = ((uint32_t)v) << 16;
  return __builtin_bit_cast(float, u);
}

// ---------------- fused f32 -> bf16 converts ----------------
__global__ void cvt_all(const float4* __restrict__ x, const float4* __restrict__ wq,
                        const float4* __restrict__ wp, ushort4* __restrict__ xb,
                        ushort4* __restrict__ wqb, ushort4* __restrict__ wpb) {
  const int NX = Mr * Cc / 4, NQ = C3 * Cc / 4, NP = Cc * Cc / 4;
  int i = blockIdx.x * blockDim.x + threadIdx.x;
  const int stride = gridDim.x * blockDim.x;
  for (; i < NX + NQ + NP; i += stride) {
    const float4* src; ushort4* dst; int j;
    if (i < NX)           { src = x;  dst = xb;  j = i; }
    else if (i < NX + NQ) { src = wq; dst = wqb; j = i - NX; }
    else                  { src = wp; dst = wpb; j = i - NX - NQ; }
    float4 v = src[j];
    ushort4 o;
    o.x = f2bf_rne(v.x); o.y = f2bf_rne(v.y);
    o.z = f2bf_rne(v.z); o.w = f2bf_rne(v.w);
    dst[j] = o;
  }
}

// ---------------- async global->LDS, 16B per lane ----------------
DEVFN void gload_lds16(const void* g, void* l) {
  __builtin_amdgcn_global_load_lds(
      (const __attribute__((address_space(1))) uint32_t*)g,
      (__attribute__((address_space(3))) uint32_t*)l,
      16, 0, 0);
}

// =====================================================================
// 256x256 bf16 NT GEMM — R2 structure (108.6 us, reproduced 4x), with
// ONE change this round (R12 A/B): MFMA operand-swap + vectorized
// ushort4 epilogue (128 scalar stores -> 32 vector stores per thread).
// Staging, LDS layout, ring, vmcnt discipline byte-identical to R2/R11.
// If this regresses to ~119 us, the R3 regression is attributed to the
// swap and the next step is revert-to-R11.
// =====================================================================
template <bool OUT_F32>
__global__ __launch_bounds__(512, 2)
void gemm256(const u16* __restrict__ A, const u16* __restrict__ Bw,
             void* __restrict__ Cout, const float* __restrict__ bias,
             int Ndim, int K) {
  constexpr int SLOT = 32768;
  __shared__ char lds[4 * SLOT];   // 128 KiB

  const int nTn = Ndim >> 8;
  const int nwg = gridDim.x;
  const int bid = blockIdx.x;
  const int wgid = (bid & 7) * (nwg >> 3) + (bid >> 3);   // XCD swizzle (nwg%8==0)
  const int tm = wgid / nTn, tn = wgid % nTn;

  const int t = threadIdx.x;
  const int l = t & 63;
  const int w = t >> 6;
  const int wr = w >> 2;         // M half of tile
  const int wcq = w & 3;         // N quarter of tile
  const int lr = l & 15;

  const int NPH = K >> 5;

  const int srow = l >> 2;
  const int scol = 8 * ((l & 3) ^ (srow & 3));
  const u16* pA0 = A  + (size_t)(tm * 256 +       w * 16 + srow) * K + scol;
  const u16* pA1 = A  + (size_t)(tm * 256 + 128 + w * 16 + srow) * K + scol;
  const u16* pB0 = Bw + (size_t)(tn * 256 +       w * 16 + srow) * K + scol;
  const u16* pB1 = Bw + (size_t)(tn * 256 + 128 + w * 16 + srow) * K + scol;

  const int lane_off = lr * 64 + (((l >> 4) * 16) ^ ((lr & 3) << 4));

  f32x4 acc[8][4];
  #pragma unroll
  for (int m = 0; m < 8; ++m)
    #pragma unroll
    for (int n = 0; n < 4; ++n)
      acc[m][n] = f32x4{0.f, 0.f, 0.f, 0.f};

  #pragma unroll
  for (int q = 0; q < 3; ++q) {
    char* dA = &lds[q * SLOT + w * 1024];
    char* dB = &lds[q * SLOT + 16384 + w * 1024];
    const size_t ko = (size_t)q * 32;
    gload_lds16(pA0 + ko, dA);
    gload_lds16(pA1 + ko, dA + 8192);
    gload_lds16(pB0 + ko, dB);
    gload_lds16(pB1 + ko, dB + 8192);
  }

#define GPHASE(VMSTR, PF_COND)                                                \
  do {                                                                        \
    asm volatile(VMSTR ::: "memory");                                         \
    __builtin_amdgcn_s_barrier();                                             \
    asm volatile("" ::: "memory");                                            \
    const char* ab = &lds[(p & 3) * SLOT] + wr * 8192 + lane_off;             \
    const char* bb = &lds[(p & 3) * SLOT + 16384] + wcq * 4096 + lane_off;    \
    bf16x8 af[8], bf[4];                                                      \
    _Pragma("unroll")                                                         \
    for (int m = 0; m < 8; ++m)                                               \
      af[m] = *reinterpret_cast<const bf16x8*>(ab + m * 1024);                \
    _Pragma("unroll")                                                         \
    for (int n = 0; n < 4; ++n)                                               \
      bf[n] = *reinterpret_cast<const bf16x8*>(bb + n * 1024);                \
    if (PF_COND) {                                                            \
      const int ps = (p + 3) & 3;                                             \
      char* dA = &lds[ps * SLOT + w * 1024];                                  \
      char* dB = &lds[ps * SLOT + 16384 + w * 1024];                          \
      const size_t ko = (size_t)(p + 3) * 32;                                 \
      gload_lds16(pA0 + ko, dA);                                              \
      gload_lds16(pA1 + ko, dA + 8192);                                       \
      gload_lds16(pB0 + ko, dB);                                              \
      gload_lds16(pB1 + ko, dB + 8192);                                       \
    }                                                                         \
    __builtin_amdgcn_s_setprio(1);                                            \
    _Pragma("unroll")                                                         \
    for (int m = 0; m < 8; ++m)                                               \
      _Pragma("unroll")                                                       \
      for (int n = 0; n < 4; ++n)                                             \
        acc[m][n] = __builtin_amdgcn_mfma_f32_16x16x32_bf16(bf[n], af[m],     \
                                                            acc[m][n], 0,0,0);\
    __builtin_amdgcn_s_setprio(0);                                            \
    asm volatile("" ::: "memory");                                            \
  } while (0)

  int p = 0;
  for (; p < NPH - 2; ++p) GPHASE("s_waitcnt vmcnt(8)", (p + 3 < NPH));
  GPHASE("s_waitcnt vmcnt(4)", false); ++p;
  GPHASE("s_waitcnt vmcnt(0)", false); ++p;
#undef GPHASE

  // epilogue (operand-swapped layout, verified R3/R6/R10): lane l,
  // frag (m,n), reg j -> C[m*16 + (l&15)][n*16 + (l>>4)*4 + j]
  const int grow0 = tm * 256 + wr * 128 + lr;
  const int gcol0 = tn * 256 + wcq * 64 + (l >> 4) * 4;
  #pragma unroll
  for (int m = 0; m < 8; ++m) {
    const int row = grow0 + m * 16;
    #pragma unroll
    for (int n = 0; n < 4; ++n) {
      const int col = gcol0 + n * 16;
      if constexpr (OUT_F32) {
        float* O = (float*)Cout;
        const float4 bv = *reinterpret_cast<const float4*>(&bias[col]);
        float4 o;
        o.x = acc[m][n][0] + bv.x;
        o.y = acc[m][n][1] + bv.y;
        o.z = acc[m][n][2] + bv.z;
        o.w = acc[m][n][3] + bv.w;
        *reinterpret_cast<float4*>(&O[(size_t)row * Ndim + col]) = o;
      } else {
        u16* O = (u16*)Cout;
        ushort4 o;
        o.x = f2bf_rne(acc[m][n][0]);
        o.y = f2bf_rne(acc[m][n][1]);
        o.z = f2bf_rne(acc[m][n][2]);
        o.w = f2bf_rne(acc[m][n][3]);
        *reinterpret_cast<ushort4*>(&O[(size_t)row * Ndim + col]) = o;
      }
    }
  }
}

// =====================================================================
// 128x128 bf16 NT GEMM, BK=64, 4 waves, 2-slot dbuf, 2 blocks/CU
// (R10/R11, verified; GEMM2 ~46 us).
// =====================================================================
template <int BM, int BN, int WM, int WN, bool OUT_F32>
__global__ __launch_bounds__(WM * WN * 64, 2)
void gemm_bk64(const u16* __restrict__ A, const u16* __restrict__ Bw,
               void* __restrict__ Cout, const float* __restrict__ bias,
               int Ndim, int K) {
  constexpr int NT = WM * WN * 64;
  constexpr int MF = BM / WM / 16;
  constexpr int NF = BN / WN / 16;
  constexpr int SLOT = (BM + BN) * 128;
  static_assert(4 * (NT / 8) == BM && BM == BN, "staging geometry");
  __shared__ char lds[2 * SLOT];

  const int nTn = Ndim / BN;
  const int nwg = gridDim.x;
  const int bid = blockIdx.x;
  const int wgid = (bid & 7) * (nwg >> 3) + (bid >> 3);
  const int tm = wgid / nTn, tn = wgid % nTn;

  const int t = threadIdx.x;
  const int l = t & 63;
  const int w = t >> 6;
  const int wr = w / WN;
  const int wc = w % WN;

  const int NSL = K >> 6;

  const int srA = t >> 3;
  const int sw8 = ((t & 7) ^ ((t >> 3) & 7)) * 8;
  const u16* baseA = A  + (size_t)(tm * BM) * K + sw8;
  const u16* baseB = Bw + (size_t)(tn * BN) * K + sw8;

  const int lt0 = (l & 15) * 128 + (((l >> 4)    ) ^ (l & 7)) * 16;
  const int lt1 = (l & 15) * 128 + (((l >> 4) + 4) ^ (l & 7)) * 16;

  f32x4 acc[MF][NF];
  #pragma unroll
  for (int m = 0; m < MF; ++m)
    #pragma unroll
    for (int n = 0; n < NF; ++n)
      acc[m][n] = f32x4{0.f, 0.f, 0.f, 0.f};

#define STAGE(SL, P)                                                          \
  do {                                                                        \
    char* d = lds + (SL) * SLOT + t * 16;                                     \
    const size_t ko = (size_t)(P) * 64;                                       \
    _Pragma("unroll")                                                         \
    for (int k = 0; k < 4; ++k)                                               \
      gload_lds16(baseA + (size_t)(k * (NT / 8) + srA) * K + ko,              \
                  d + k * NT * 16);                                           \
    _Pragma("unroll")                                                         \
    for (int k = 0; k < 4; ++k)                                               \
      gload_lds16(baseB + (size_t)(k * (NT / 8) + srA) * K + ko,              \
                  d + (k + 4) * NT * 16);                                     \
  } while (0)

  STAGE(0, 0);

  for (int p = 0; p < NSL; ++p) {
    asm volatile("s_waitcnt vmcnt(0)" ::: "memory");
    __builtin_amdgcn_s_barrier();

    const char* ab = lds + (p & 1) * SLOT + wr * (BM / WM) * 128;
    const char* bb = lds + (p & 1) * SLOT + BM * 128 + wc * (BN / WN) * 128;

    bf16x8 af[MF], bf[NF];
    #pragma unroll
    for (int m = 0; m < MF; ++m)
      af[m] = *reinterpret_cast<const bf16x8*>(ab + m * 2048 + lt0);
    #pragma unroll
    for (int n = 0; n < NF; ++n)
      bf[n] = *reinterpret_cast<const bf16x8*>(bb + n * 2048 + lt0);

    if (p + 1 < NSL) STAGE((p + 1) & 1, p + 1);

    __builtin_amdgcn_s_setprio(1);
    #pragma unroll
    for (int m = 0; m < MF; ++m)
      #pragma unroll
      for (int n = 0; n < NF; ++n)
        acc[m][n] = __builtin_amdgcn_mfma_f32_16x16x32_bf16(bf[n], af[m],
                                                            acc[m][n], 0, 0, 0);
    __builtin_amdgcn_s_setprio(0);

    #pragma unroll
    for (int m = 0; m < MF; ++m)
      af[m] = *reinterpret_cast<const bf16x8*>(ab + m * 2048 + lt1);
    #pragma unroll
    for (int n = 0; n < NF; ++n)
      bf[n] = *reinterpret_cast<const bf16x8*>(bb + n * 2048 + lt1);

    __builtin_amdgcn_s_setprio(1);
    #pragma unroll
    for (int m = 0; m < MF; ++m)
      #pragma unroll
      for (int n = 0; n < NF; ++n)
        acc[m][n] = __builtin_amdgcn_mfma_f32_16x16x32_bf16(bf[n], af[m],
                                                            acc[m][n], 0, 0, 0);
    __builtin_amdgcn_s_setprio(0);
  }
#undef STAGE

  const int grow0 = tm * BM + wr * (BM / WM) + (l & 15);
  const int gcol0 = tn * BN + wc * (BN / WN) + (l >> 4) * 4;
  #pragma unroll
  for (int m = 0; m < MF; ++m) {
    const int row = grow0 + m * 16;
    #pragma unroll
    for (int n = 0; n < NF; ++n) {
      const int col = gcol0 + n * 16;
      if constexpr (OUT_F32) {
        float* O = (float*)Cout;
        const float4 bv = *reinterpret_cast<const float4*>(&bias[col]);
        float4 o;
        o.x = acc[m][n][0] + bv.x;
        o.y = acc[m][n][1] + bv.y;
        o.z = acc[m][n][2] + bv.z;
        o.w = acc[m][n][3] + bv.w;
        *reinterpret_cast<float4*>(&O[(size_t)row * Ndim + col]) = o;
      } else {
        u16* O = (u16*)Cout;
        ushort4 o;
        o.x = f2bf_rne(acc[m][n][0]);
        o.y = f2bf_rne(acc[m][n][1]);
        o.z = f2bf_rne(acc[m][n][2]);
        o.w = f2bf_rne(acc[m][n][3]);
        *reinterpret_cast<ushort4*>(&O[(size_t)row * Ndim + col]) = o;
      }
    }
  }
}

// =====================================================================
// local 3x3 dilated attention, 4x-vectorized (R9, verified).
// =====================================================================
__global__ __launch_bounds__(256)
void attn_local4(const u16* __restrict__ qkv, u16* __restrict__ y) {
  const int t = threadIdx.x;
  const int l = t & 63;
  int wid = blockIdx.x * 4 + (t >> 6);      // [0, 3*8*1024)
  const int w = wid & (NB - 1); wid >>= 10;
  const int b = wid & 7; wid >>= 3;
  const int dil = wid;                      // 0..2

  const int colq = dil * 256 + l * 4;       // 4 consecutive dims, head l>>4
  float q[3][4], k[3][4], v[3][4];
  #pragma unroll
  for (int i = 0; i < 3; ++i) {
    const size_t row = (size_t)(b * Nn + i * NB + w) * C3;
    const ushort4 q4 = *reinterpret_cast<const ushort4*>(&qkv[row + colq]);
    const ushort4 k4 = *reinterpret_cast<const ushort4*>(&qkv[row + 768 + colq]);
    const ushort4 v4 = *reinterpret_cast<const ushort4*>(&qkv[row + 1536 + colq]);
    q[i][0] = bf2f(q4.x); q[i][1] = bf2f(q4.y); q[i][2] = bf2f(q4.z); q[i][3] = bf2f(q4.w);
    k[i][0] = bf2f(k4.x); k[i][1] = bf2f(k4.y); k[i][2] = bf2f(k4.z); k[i][3] = bf2f(k4.w);
    v[i][0] = bf2f(v4.x); v[i][1] = bf2f(v4.y); v[i][2] = bf2f(v4.z); v[i][3] = bf2f(v4.w);
  }

  float s[3][3];
  #pragma unroll
  for (int i = 0; i < 3; ++i)
    #pragma unroll
    for (int j = 0; j < 3; ++j) {
      float p = q[i][0] * k[j][0] + q[i][1] * k[j][1]
              + q[i][2] * k[j][2] + q[i][3] * k[j][3];
      p += __shfl_xor(p, 1, 64);
      p += __shfl_xor(p, 2, 64);
      p += __shfl_xor(p, 4, 64);
      p += __shfl_xor(p, 8, 64);
      s[i][j] = p * 0.125f;   // hd=64 -> scale 1/8
    }

  #pragma unroll
  for (int i = 0; i < 3; ++i) {
    const float mx = fmaxf(fmaxf(s[i][0], s[i][1]), s[i][2]);
    const float e0 = __expf(s[i][0] - mx);
    const float e1 = __expf(s[i][1] - mx);
    const float e2 = __expf(s[i][2] - mx);
    const float inv = 1.0f / (e0 + e1 + e2);
    ushort4 o4;
    u16* po = &o4.x;
    #pragma unroll
    for (int e = 0; e < 4; ++e)
      po[e] = f2bf_rne((e0 * v[0][e] + e1 * v[1][e] + e2 * v[2][e]) * inv);
    const int linear = (l >> 4) * 192 + i * 64 + (l & 15) * 4;
    const int nout = w * 3 + (linear >> 8);
    const int dd = linear & 255;
    *reinterpret_cast<ushort4*>(
        &y[(size_t)(b * Nn + nout) * Cc + dil * 256 + dd]) = o4;
  }
}

extern "C" void kernel_launch(void* const* d_in, const int* in_sizes, int n_in,
                              void* d_out, int out_size, void* d_ws, size_t ws_size,
                              hipStream_t stream) {
  const float* x      = (const float*)d_in[0];
  const float* qkv_w  = (const float*)d_in[1];
  const float* proj_w = (const float*)d_in[2];
  const float* proj_b = (const float*)d_in[3];

  char* ws = (char*)d_ws;
  u16* wq_b = (u16*)(ws);                      //  2304*768 bf16
  u16* wp_b = (u16*)(ws + 3538944);            //   768*768 bf16
  u16* xb   = (u16*)(ws + 4718592);            // 24576*768 bf16 (reused as yb)
  u16* qkvb = (u16*)(ws + 42467328);           // 24576*2304 bf16
  u16* yb   = xb;

  cvt_all<<<2048, 256, 0, stream>>>((const float4*)x, (const float4*)qkv_w,
                                    (const float4*)proj_w, (ushort4*)xb,
                                    (ushort4*)wq_b, (ushort4*)wp_b);

  // GEMM1: qkvb[M,2304] = xb[M,768] @ wq_b[2304,768]^T   (864 blocks)
  gemm256<false><<<(Mr / 256) * (C3 / 256), 512, 0, stream>>>(xb, wq_b, qkvb, nullptr, C3, Cc);

  // attention: 24576 wave-groups (4 heads each), 4 per block
  attn_local4<<<(3 * 8 * 1024) / 4, 256, 0, stream>>>(qkvb, yb);

  // GEMM2: out[M,768] = yb[M,768] @ wp_b[768,768]^T + proj_b
  gemm_bk64<128, 128, 2, 2, true>
      <<<(Mr / 128) * (Cc / 128), 256, 0, stream>>>(yb, wp_b, d_out, proj_b, Cc, Cc);
}

// Round 13
// 197.036 us; speedup vs baseline: 1.0700x; 1.0700x over previous
//
#include <hip/hip_runtime.h>
#include <stdint.h>

#define DEVFN __device__ __forceinline__

typedef unsigned short u16;
typedef __bf16 bf16_t;
typedef bf16_t bf16x8 __attribute__((ext_vector_type(8)));
typedef float  f32x4  __attribute__((ext_vector_type(4)));

static constexpr int Bb = 8, Nn = 3072, Cc = 768;
static constexpr int Mr = Bb * Nn;      // 24576 rows
static constexpr int C3 = 3 * Cc;       // 2304
static constexpr int NB = 1024;         // dilation stride

DEVFN u16 f2bf_rne(float f) {
  uint32_t u = __builtin_bit_cast(uint32_t, f);
  u += 0x7FFFu + ((u >> 16) & 1u);
  return (u16)(u >> 16);
}
DEVFN float bf2f(u16 v) {
  uint32_t u = ((uint32_t)v) << 16;
  return __builtin_bit_cast(float, u);
}

// ---------------- fused f32 -> bf16 converts ----------------
__global__ void cvt_all(const float4* __restrict__ x, const float4* __restrict__ wq,
                        const float4* __restrict__ wp, ushort4* __restrict__ xb,
                        ushort4* __restrict__ wqb, ushort4* __restrict__ wpb) {
  const int NX = Mr * Cc / 4, NQ = C3 * Cc / 4, NP = Cc * Cc / 4;
  int i = blockIdx.x * blockDim.x + threadIdx.x;
  const int stride = gridDim.x * blockDim.x;
  for (; i < NX + NQ + NP; i += stride) {
    const float4* src; ushort4* dst; int j;
    if (i < NX)           { src = x;  dst = xb;  j = i; }
    else if (i < NX + NQ) { src = wq; dst = wqb; j = i - NX; }
    else                  { src = wp; dst = wpb; j = i - NX - NQ; }
    float4 v = src[j];
    ushort4 o;
    o.x = f2bf_rne(v.x); o.y = f2bf_rne(v.y);
    o.z = f2bf_rne(v.z); o.w = f2bf_rne(v.w);
    dst[j] = o;
  }
}

// ---------------- async global->LDS, 16B per lane ----------------
DEVFN void gload_lds16(const void* g, void* l) {
  __builtin_amdgcn_global_load_lds(
      (const __attribute__((address_space(1))) uint32_t*)g,
      (__attribute__((address_space(3))) uint32_t*)l,
      16, 0, 0);
}

// =====================================================================
// 256x256 bf16 NT GEMM — R2 VERBATIM. Session best for GEMM1: 108.6 us,
// reproduced 4x (R2/R9/R11 x2 groups). Full ledger of 8 failed
// alternatives: conflict-free swizzle (+11), operand-swap (+15, R12
// isolated: MFMA operand order is load-bearing — af[m] held outer,
// bf[n] rotating schedules better), sub-phase schedule (+20), 128-tile
// 3blk/CU (+32), 16-wave (+9), BK=64 8-phase (+17), BK=64 dbuf (+7).
// 8 waves, 4-slot K=32-slice ring, counted vmcnt(8) (~2 slices latency
// tolerance), 1 barrier/slice. DO NOT TOUCH.
// =====================================================================
template <bool OUT_F32>
__global__ __launch_bounds__(512, 2)
void gemm256(const u16* __restrict__ A, const u16* __restrict__ Bw,
             void* __restrict__ Cout, const float* __restrict__ bias,
             int Ndim, int K) {
  constexpr int SLOT = 32768;
  __shared__ char lds[4 * SLOT];   // 128 KiB

  const int nTn = Ndim >> 8;
  const int nwg = gridDim.x;
  const int bid = blockIdx.x;
  const int wgid = (bid & 7) * (nwg >> 3) + (bid >> 3);   // XCD swizzle (nwg%8==0)
  const int tm = wgid / nTn, tn = wgid % nTn;

  const int t = threadIdx.x;
  const int l = t & 63;
  const int w = t >> 6;
  const int wr = w >> 2;         // M half of tile
  const int wcq = w & 3;         // N quarter of tile
  const int lr = l & 15;

  const int NPH = K >> 5;

  const int srow = l >> 2;
  const int scol = 8 * ((l & 3) ^ (srow & 3));
  const u16* pA0 = A  + (size_t)(tm * 256 +       w * 16 + srow) * K + scol;
  const u16* pA1 = A  + (size_t)(tm * 256 + 128 + w * 16 + srow) * K + scol;
  const u16* pB0 = Bw + (size_t)(tn * 256 +       w * 16 + srow) * K + scol;
  const u16* pB1 = Bw + (size_t)(tn * 256 + 128 + w * 16 + srow) * K + scol;

  const int lane_off = lr * 64 + (((l >> 4) * 16) ^ ((lr & 3) << 4));

  f32x4 acc[8][4];
  #pragma unroll
  for (int m = 0; m < 8; ++m)
    #pragma unroll
    for (int n = 0; n < 4; ++n)
      acc[m][n] = f32x4{0.f, 0.f, 0.f, 0.f};

  #pragma unroll
  for (int q = 0; q < 3; ++q) {
    char* dA = &lds[q * SLOT + w * 1024];
    char* dB = &lds[q * SLOT + 16384 + w * 1024];
    const size_t ko = (size_t)q * 32;
    gload_lds16(pA0 + ko, dA);
    gload_lds16(pA1 + ko, dA + 8192);
    gload_lds16(pB0 + ko, dB);
    gload_lds16(pB1 + ko, dB + 8192);
  }

#define GPHASE(VMSTR, PF_COND)                                                \
  do {                                                                        \
    asm volatile(VMSTR ::: "memory");                                         \
    __builtin_amdgcn_s_barrier();                                             \
    asm volatile("" ::: "memory");                                            \
    const char* ab = &lds[(p & 3) * SLOT] + wr * 8192 + lane_off;             \
    const char* bb = &lds[(p & 3) * SLOT + 16384] + wcq * 4096 + lane_off;    \
    bf16x8 af[8], bf[4];                                                      \
    _Pragma("unroll")                                                         \
    for (int m = 0; m < 8; ++m)                                               \
      af[m] = *reinterpret_cast<const bf16x8*>(ab + m * 1024);                \
    _Pragma("unroll")                                                         \
    for (int n = 0; n < 4; ++n)                                               \
      bf[n] = *reinterpret_cast<const bf16x8*>(bb + n * 1024);                \
    if (PF_COND) {                                                            \
      const int ps = (p + 3) & 3;                                             \
      char* dA = &lds[ps * SLOT + w * 1024];                                  \
      char* dB = &lds[ps * SLOT + 16384 + w * 1024];                          \
      const size_t ko = (size_t)(p + 3) * 32;                                 \
      gload_lds16(pA0 + ko, dA);                                              \
      gload_lds16(pA1 + ko, dA + 8192);                                       \
      gload_lds16(pB0 + ko, dB);                                              \
      gload_lds16(pB1 + ko, dB + 8192);                                       \
    }                                                                         \
    __builtin_amdgcn_s_setprio(1);                                            \
    _Pragma("unroll")                                                         \
    for (int m = 0; m < 8; ++m)                                               \
      _Pragma("unroll")                                                       \
      for (int n = 0; n < 4; ++n)                                             \
        acc[m][n] = __builtin_amdgcn_mfma_f32_16x16x32_bf16(af[m], bf[n],     \
                                                            acc[m][n], 0,0,0);\
    __builtin_amdgcn_s_setprio(0);                                            \
    asm volatile("" ::: "memory");                                            \
  } while (0)

  int p = 0;
  for (; p < NPH - 2; ++p) GPHASE("s_waitcnt vmcnt(8)", (p + 3 < NPH));
  GPHASE("s_waitcnt vmcnt(4)", false); ++p;
  GPHASE("s_waitcnt vmcnt(0)", false); ++p;
#undef GPHASE

  // epilogue: C/D layout col=lane&15, row=(lane>>4)*4+j
  const int rbase = tm * 256 + wr * 128 + (l >> 4) * 4;
  #pragma unroll
  for (int m = 0; m < 8; ++m) {
    #pragma unroll
    for (int n = 0; n < 4; ++n) {
      const int col = tn * 256 + wcq * 64 + n * 16 + lr;
      const int row0 = rbase + m * 16;
      if constexpr (OUT_F32) {
        float* O = (float*)Cout;
        const float bv = bias[col];
        #pragma unroll
        for (int j = 0; j < 4; ++j)
          O[(size_t)(row0 + j) * Ndim + col] = acc[m][n][j] + bv;
      } else {
        u16* O = (u16*)Cout;
        #pragma unroll
        for (int j = 0; j < 4; ++j)
          O[(size_t)(row0 + j) * Ndim + col] = f2bf_rne(acc[m][n][j]);
      }
    }
  }
}

// =====================================================================
// 128x128 bf16 NT GEMM, BK=64, 4 waves, 2-slot dbuf, 2 blocks/CU
// (R10/R11, verified; GEMM2 ~46 us).
// =====================================================================
template <int BM, int BN, int WM, int WN, bool OUT_F32>
__global__ __launch_bounds__(WM * WN * 64, 2)
void gemm_bk64(const u16* __restrict__ A, const u16* __restrict__ Bw,
               void* __restrict__ Cout, const float* __restrict__ bias,
               int Ndim, int K) {
  constexpr int NT = WM * WN * 64;
  constexpr int MF = BM / WM / 16;
  constexpr int NF = BN / WN / 16;
  constexpr int SLOT = (BM + BN) * 128;
  static_assert(4 * (NT / 8) == BM && BM == BN, "staging geometry");
  __shared__ char lds[2 * SLOT];

  const int nTn = Ndim / BN;
  const int nwg = gridDim.x;
  const int bid = blockIdx.x;
  const int wgid = (bid & 7) * (nwg >> 3) + (bid >> 3);
  const int tm = wgid / nTn, tn = wgid % nTn;

  const int t = threadIdx.x;
  const int l = t & 63;
  const int w = t >> 6;
  const int wr = w / WN;
  const int wc = w % WN;

  const int NSL = K >> 6;

  const int srA = t >> 3;
  const int sw8 = ((t & 7) ^ ((t >> 3) & 7)) * 8;
  const u16* baseA = A  + (size_t)(tm * BM) * K + sw8;
  const u16* baseB = Bw + (size_t)(tn * BN) * K + sw8;

  const int lt0 = (l & 15) * 128 + (((l >> 4)    ) ^ (l & 7)) * 16;
  const int lt1 = (l & 15) * 128 + (((l >> 4) + 4) ^ (l & 7)) * 16;

  f32x4 acc[MF][NF];
  #pragma unroll
  for (int m = 0; m < MF; ++m)
    #pragma unroll
    for (int n = 0; n < NF; ++n)
      acc[m][n] = f32x4{0.f, 0.f, 0.f, 0.f};

#define STAGE(SL, P)                                                          \
  do {                                                                        \
    char* d = lds + (SL) * SLOT + t * 16;                                     \
    const size_t ko = (size_t)(P) * 64;                                       \
    _Pragma("unroll")                                                         \
    for (int k = 0; k < 4; ++k)                                               \
      gload_lds16(baseA + (size_t)(k * (NT / 8) + srA) * K + ko,              \
                  d + k * NT * 16);                                           \
    _Pragma("unroll")                                                         \
    for (int k = 0; k < 4; ++k)                                               \
      gload_lds16(baseB + (size_t)(k * (NT / 8) + srA) * K + ko,              \
                  d + (k + 4) * NT * 16);                                     \
  } while (0)

  STAGE(0, 0);

  for (int p = 0; p < NSL; ++p) {
    asm volatile("s_waitcnt vmcnt(0)" ::: "memory");
    __builtin_amdgcn_s_barrier();

    const char* ab = lds + (p & 1) * SLOT + wr * (BM / WM) * 128;
    const char* bb = lds + (p & 1) * SLOT + BM * 128 + wc * (BN / WN) * 128;

    bf16x8 af[MF], bf[NF];
    #pragma unroll
    for (int m = 0; m < MF; ++m)
      af[m] = *reinterpret_cast<const bf16x8*>(ab + m * 2048 + lt0);
    #pragma unroll
    for (int n = 0; n < NF; ++n)
      bf[n] = *reinterpret_cast<const bf16x8*>(bb + n * 2048 + lt0);

    if (p + 1 < NSL) STAGE((p + 1) & 1, p + 1);

    __builtin_amdgcn_s_setprio(1);
    #pragma unroll
    for (int m = 0; m < MF; ++m)
      #pragma unroll
      for (int n = 0; n < NF; ++n)
        acc[m][n] = __builtin_amdgcn_mfma_f32_16x16x32_bf16(bf[n], af[m],
                                                            acc[m][n], 0, 0, 0);
    __builtin_amdgcn_s_setprio(0);

    #pragma unroll
    for (int m = 0; m < MF; ++m)
      af[m] = *reinterpret_cast<const bf16x8*>(ab + m * 2048 + lt1);
    #pragma unroll
    for (int n = 0; n < NF; ++n)
      bf[n] = *reinterpret_cast<const bf16x8*>(bb + n * 2048 + lt1);

    __builtin_amdgcn_s_setprio(1);
    #pragma unroll
    for (int m = 0; m < MF; ++m)
      #pragma unroll
      for (int n = 0; n < NF; ++n)
        acc[m][n] = __builtin_amdgcn_mfma_f32_16x16x32_bf16(bf[n], af[m],
                                                            acc[m][n], 0, 0, 0);
    __builtin_amdgcn_s_setprio(0);
  }
#undef STAGE

  const int grow0 = tm * BM + wr * (BM / WM) + (l & 15);
  const int gcol0 = tn * BN + wc * (BN / WN) + (l >> 4) * 4;
  #pragma unroll
  for (int m = 0; m < MF; ++m) {
    const int row = grow0 + m * 16;
    #pragma unroll
    for (int n = 0; n < NF; ++n) {
      const int col = gcol0 + n * 16;
      if constexpr (OUT_F32) {
        float* O = (float*)Cout;
        const float4 bv = *reinterpret_cast<const float4*>(&bias[col]);
        float4 o;
        o.x = acc[m][n][0] + bv.x;
        o.y = acc[m][n][1] + bv.y;
        o.z = acc[m][n][2] + bv.z;
        o.w = acc[m][n][3] + bv.w;
        *reinterpret_cast<float4*>(&O[(size_t)row * Ndim + col]) = o;
      } else {
        u16* O = (u16*)Cout;
        ushort4 o;
        o.x = f2bf_rne(acc[m][n][0]);
        o.y = f2bf_rne(acc[m][n][1]);
        o.z = f2bf_rne(acc[m][n][2]);
        o.w = f2bf_rne(acc[m][n][3]);
        *reinterpret_cast<ushort4*>(&O[(size_t)row * Ndim + col]) = o;
      }
    }
  }
}

// =====================================================================
// local 3x3 dilated attention, 4x-vectorized (R9, verified).
// =====================================================================
__global__ __launch_bounds__(256)
void attn_local4(const u16* __restrict__ qkv, u16* __restrict__ y) {
  const int t = threadIdx.x;
  const int l = t & 63;
  int wid = blockIdx.x * 4 + (t >> 6);      // [0, 3*8*1024)
  const int w = wid & (NB - 1); wid >>= 10;
  const int b = wid & 7; wid >>= 3;
  const int dil = wid;                      // 0..2

  const int colq = dil * 256 + l * 4;       // 4 consecutive dims, head l>>4
  float q[3][4], k[3][4], v[3][4];
  #pragma unroll
  for (int i = 0; i < 3; ++i) {
    const size_t row = (size_t)(b * Nn + i * NB + w) * C3;
    const ushort4 q4 = *reinterpret_cast<const ushort4*>(&qkv[row + colq]);
    const ushort4 k4 = *reinterpret_cast<const ushort4*>(&qkv[row + 768 + colq]);
    const ushort4 v4 = *reinterpret_cast<const ushort4*>(&qkv[row + 1536 + colq]);
    q[i][0] = bf2f(q4.x); q[i][1] = bf2f(q4.y); q[i][2] = bf2f(q4.z); q[i][3] = bf2f(q4.w);
    k[i][0] = bf2f(k4.x); k[i][1] = bf2f(k4.y); k[i][2] = bf2f(k4.z); k[i][3] = bf2f(k4.w);
    v[i][0] = bf2f(v4.x); v[i][1] = bf2f(v4.y); v[i][2] = bf2f(v4.z); v[i][3] = bf2f(v4.w);
  }

  float s[3][3];
  #pragma unroll
  for (int i = 0; i < 3; ++i)
    #pragma unroll
    for (int j = 0; j < 3; ++j) {
      float p = q[i][0] * k[j][0] + q[i][1] * k[j][1]
              + q[i][2] * k[j][2] + q[i][3] * k[j][3];
      p += __shfl_xor(p, 1, 64);
      p += __shfl_xor(p, 2, 64);
      p += __shfl_xor(p, 4, 64);
      p += __shfl_xor(p, 8, 64);
      s[i][j] = p * 0.125f;   // hd=64 -> scale 1/8
    }

  #pragma unroll
  for (int i = 0; i < 3; ++i) {
    const float mx = fmaxf(fmaxf(s[i][0], s[i][1]), s[i][2]);
    const float e0 = __expf(s[i][0] - mx);
    const float e1 = __expf(s[i][1] - mx);
    const float e2 = __expf(s[i][2] - mx);
    const float inv = 1.0f / (e0 + e1 + e2);
    ushort4 o4;
    u16* po = &o4.x;
    #pragma unroll
    for (int e = 0; e < 4; ++e)
      po[e] = f2bf_rne((e0 * v[0][e] + e1 * v[1][e] + e2 * v[2][e]) * inv);
    const int linear = (l >> 4) * 192 + i * 64 + (l & 15) * 4;
    const int nout = w * 3 + (linear >> 8);
    const int dd = linear & 255;
    *reinterpret_cast<ushort4*>(
        &y[(size_t)(b * Nn + nout) * Cc + dil * 256 + dd]) = o4;
  }
}

extern "C" void kernel_launch(void* const* d_in, const int* in_sizes, int n_in,
                              void* d_out, int out_size, void* d_ws, size_t ws_size,
                              hipStream_t stream) {
  const float* x      = (const float*)d_in[0];
  const float* qkv_w  = (const float*)d_in[1];
  const float* proj_w = (const float*)d_in[2];
  const float* proj_b = (const float*)d_in[3];

  char* ws = (char*)d_ws;
  u16* wq_b = (u16*)(ws);                      //  2304*768 bf16
  u16* wp_b = (u16*)(ws + 3538944);            //   768*768 bf16
  u16* xb   = (u16*)(ws + 4718592);            // 24576*768 bf16 (reused as yb)
  u16* qkvb = (u16*)(ws + 42467328);           // 24576*2304 bf16
  u16* yb   = xb;

  cvt_all<<<2048, 256, 0, stream>>>((const float4*)x, (const float4*)qkv_w,
                                    (const float4*)proj_w, (ushort4*)xb,
                                    (ushort4*)wq_b, (ushort4*)wp_b);

  // GEMM1: qkvb[M,2304] = xb[M,768] @ wq_b[2304,768]^T   (R2 verbatim, 864 blocks)
  gemm256<false><<<(Mr / 256) * (C3 / 256), 512, 0, stream>>>(xb, wq_b, qkvb, nullptr, C3, Cc);

  // attention: 24576 wave-groups (4 heads each), 4 per block
  attn_local4<<<(3 * 8 * 1024) / 4, 256, 0, stream>>>(qkvb, yb);

  // GEMM2: out[M,768] = yb[M,768] @ wp_b[768,768]^T + proj_b
  // 128^2 tile, BK=64, 1152 blocks, 4 waves, 2 blk/CU (R10, verified)
  gemm_bk64<128, 128, 2, 2, true>
      <<<(Mr / 128) * (Cc / 128), 256, 0, stream>>>(yb, wp_b, d_out, proj_b, Cc, Cc);
}